// Round 10
// baseline (297.880 us; speedup 1.0000x reference)
//
#include <hip/hip_runtime.h>

// Problem: B=4096, N=50, D=128, R=3, K=128, 2D=256, RD=768
// out[b,n] = sum_d ao_in[b,n,d] * v[b, s[b,n], d]
//   v[b,r,d] = sum_{d'} ui_in[b,d'] * M[r,d,d'] + c[r,d]
//   M[r,d,d'] = sum_k w_aor[r,d,k] * w_uir[r,d',k]
//   c[r,d]    = sum_k w_aor[r,d,k] * r_param[r,k]
//
// ws layout (floats):
//   v    : [4096][768]   at offset 0
//   w2t  : [768][256]    at 4096*768    row rd=r*256+d, col d'
//   cvec : [768]         after w2t
//
// JOURNAL:
//  r2: vproj reg-staged 64x64 (4x4/thr), VGPR 184, 89us. score v1 84us.
//  r6: launch_bounds(256,3) on vproj -> SPILLS (WRITE 849MB), 410us.
//  r8: gl_lds + (256,4) on vproj -> SPILLS (WRITE 1.35GB), 670us.
//      RULE: never force waves/EU below natural pressure.
//  r9: vproj v5 64x32 tile 4x2/thr, no bounds: ~65us (out of top-5), clean.
//      score v3 reg-hoist FAILED: VGPR=36 proves compiler SANK the 14
//      hoisted loads; dur/FETCH identical to r1 (84us, 109MB, 1.35TB/s).
//      LESSON: register prefetch cannot be forced at HIP level.
//  r10: score v4 = persistent 512 blocks x 8 b; per-b DMA staging via
//      global_load_lds (no dest regs -> unsinkable; MLP from DMA queue);
//      60.7KB LDS -> 2 blocks/CU; overlap via block TLP. m97 pattern.

#define TWO_D 256
#define RD 768

typedef __attribute__((address_space(1))) const unsigned int g_u32;
typedef __attribute__((address_space(3))) unsigned int l_u32;

static __device__ __forceinline__ void gl_lds16(const void* g, void* l) {
    // async global->LDS: per-lane GLOBAL src, wave-uniform LDS dest + lane*16
    __builtin_amdgcn_global_load_lds((g_u32*)g, (l_u32*)l, 16, 0, 0);
}

// ---------------- Kernel A: M + c precompute (GEMM 256x256x128 per r) --------
__global__ __launch_bounds__(256) void relproj_kernel(
    const float* __restrict__ w_aor, const float* __restrict__ w_uir,
    const float* __restrict__ r_param, float* __restrict__ w2t,
    float* __restrict__ cvec)
{
    const int r  = blockIdx.z;
    const int d0 = blockIdx.x * 64;   // m-dim: d   (rows of w_aor[r])
    const int p0 = blockIdx.y * 64;   // n-dim: d'  (rows of w_uir[r])
    const int tid = threadIdx.x;
    const int tx = tid & 15, ty = tid >> 4;

    __shared__ float4 a4[64][16];
    __shared__ float4 b4[64][16];

    float acc[4][4];
#pragma unroll
    for (int i = 0; i < 4; ++i)
#pragma unroll
        for (int j = 0; j < 4; ++j) acc[i][j] = 0.f;

    const float* Am = w_aor + (size_t)r * 256 * 128;
    const float* Bm = w_uir + (size_t)r * 256 * 128;

    for (int ks = 0; ks < 2; ++ks) {
        const int kb = ks * 64;
        __syncthreads();
#pragma unroll
        for (int i = 0; i < 4; ++i) {
            int f = tid + i * 256;          // [0,1024)
            int row = f >> 4, k4 = f & 15;
            int slot = k4 ^ ((row >> 2) & 15);
            a4[row][slot] = *(const float4*)(Am + (size_t)(d0 + row) * 128 + kb + k4 * 4);
            b4[row][slot] = *(const float4*)(Bm + (size_t)(p0 + row) * 128 + kb + k4 * 4);
        }
        __syncthreads();
#pragma unroll
        for (int k4 = 0; k4 < 16; ++k4) {
            float4 av[4], bv[4];
#pragma unroll
            for (int i = 0; i < 4; ++i) { int m = ty * 4 + i; av[i] = a4[m][k4 ^ ((m >> 2) & 15)]; }
#pragma unroll
            for (int j = 0; j < 4; ++j) { int n = tx * 4 + j; bv[j] = b4[n][k4 ^ ((n >> 2) & 15)]; }
#pragma unroll
            for (int i = 0; i < 4; ++i)
#pragma unroll
                for (int j = 0; j < 4; ++j)
                    acc[i][j] += av[i].x * bv[j].x + av[i].y * bv[j].y +
                                 av[i].z * bv[j].z + av[i].w * bv[j].w;
        }
    }

#pragma unroll
    for (int i = 0; i < 4; ++i) {
        int m = ty * 4 + i;                          // d index within tile
        float4 o = make_float4(acc[i][0], acc[i][1], acc[i][2], acc[i][3]);
        *(float4*)(w2t + (size_t)(r * 256 + d0 + m) * 256 + p0 + tx * 4) = o;
    }

    // bias c[r*256+d] computed by blocks with p-tile 0
    if (blockIdx.y == 0 && tid < 64) {
        int d = d0 + tid;
        const float* ar = Am + (size_t)d * 128;
        const float* rp = r_param + r * 128;
        float ssum = 0.f;
#pragma unroll 4
        for (int kk = 0; kk < 128; ++kk) ssum += ar[kk] * rp[kk];
        cvec[r * 256 + d] = ssum;
    }
}

// ---------------- Kernel B: v = ui_in @ w2t^T + c  (4096 x 768 x 256) --------
// v5 (r9, measured good ~65us): 64m x 32n tile, 4m x 2n per thread,
// reg-staged XOR-swizzled LDS, NO launch_bounds force. Unchanged.
__global__ __launch_bounds__(256) void vproj_kernel(
    const float* __restrict__ u_emb, const float* __restrict__ i_emb,
    const float* __restrict__ w2t, const float* __restrict__ cvec,
    float* __restrict__ v)
{
    const int b0 = blockIdx.x * 64;   // m: batch rows
    const int n0 = blockIdx.y * 32;   // n: rd columns
    const int tid = threadIdx.x;
    const int tx = tid & 15, ty = tid >> 4;

    __shared__ float4 a4[64][16];     // 64 rows x 64 floats  (16 KB)
    __shared__ float4 b4[32][16];     // 32 rows x 64 floats  ( 8 KB)

    float acc[4][2];
#pragma unroll
    for (int i = 0; i < 4; ++i) { acc[i][0] = 0.f; acc[i][1] = 0.f; }

    for (int ks = 0; ks < 4; ++ks) {
        const float* srcA = ((ks < 2) ? u_emb : i_emb) + (ks & 1) * 64;
        const float* srcB = w2t + ks * 64;
        __syncthreads();
        // stage A: 1024 float4 = 4/thread
#pragma unroll
        for (int i = 0; i < 4; ++i) {
            int f = tid + i * 256;
            int row = f >> 4, k4 = f & 15;
            a4[row][k4 ^ ((row >> 2) & 15)] =
                *(const float4*)(srcA + (size_t)(b0 + row) * 128 + k4 * 4);
        }
        // stage B: 512 float4 = 2/thread
#pragma unroll
        for (int i = 0; i < 2; ++i) {
            int f = tid + i * 256;
            int row = f >> 4, k4 = f & 15;
            b4[row][k4 ^ ((row >> 2) & 15)] =
                *(const float4*)(srcB + (size_t)(n0 + row) * 256 + k4 * 4);
        }
        __syncthreads();
#pragma unroll
        for (int k4 = 0; k4 < 16; ++k4) {
            float4 av[4], bv[2];
#pragma unroll
            for (int i = 0; i < 4; ++i) { int m = ty * 4 + i; av[i] = a4[m][k4 ^ ((m >> 2) & 15)]; }
#pragma unroll
            for (int j = 0; j < 2; ++j) { int n = tx * 2 + j; bv[j] = b4[n][k4 ^ ((n >> 2) & 15)]; }
#pragma unroll
            for (int i = 0; i < 4; ++i)
#pragma unroll
                for (int j = 0; j < 2; ++j)
                    acc[i][j] += av[i].x * bv[j].x + av[i].y * bv[j].y +
                                 av[i].z * bv[j].z + av[i].w * bv[j].w;
        }
    }

    const float2 cb = *(const float2*)(cvec + n0 + tx * 2);
#pragma unroll
    for (int i = 0; i < 4; ++i) {
        int m = ty * 4 + i;
        float2 o = make_float2(acc[i][0] + cb.x, acc[i][1] + cb.y);
        *(float2*)(v + (size_t)(b0 + m) * RD + n0 + tx * 2) = o;
    }
}

// ---------------- Kernel C: out[b,n] = dot(ao_in[b,n], v[b, s[b,n]]) ---------
// v4: persistent 512 blocks x 8 b. Per b: each wave DMA-stages its own
// 14-row a/o slice via global_load_lds (no dest VGPRs -> compiler cannot
// sink; DMA queue provides MLP); wave0 stages v[b] (shared, 3KB).
// __syncthreads drains vmcnt (m97 pattern). Compute fully from LDS:
// half-waves handle even/odd rows, 5-step shfl reduce... full 6-step over 64.
// LDS 60.7KB -> 2 blocks/CU, 512 blocks = exactly one residency round;
// block-level TLP overlaps one block's DMA wait with the other's compute.
__global__ __launch_bounds__(256) void score_kernel(
    const float* __restrict__ a_emb, const float* __restrict__ o_emb,
    const float* __restrict__ v, const int* __restrict__ s,
    float* __restrict__ out)
{
    __shared__ float aL[4][1792];   // per wave: 14 rows x 128 floats (7KB)
    __shared__ float oL[4][1792];
    __shared__ float vL[768];       // v[b][0..767], shared across waves
    __shared__ int   sL[64];

    const int tid = threadIdx.x;
    const int w = tid >> 6, l = tid & 63;
    const int ll = l & 31, half = l >> 5;
    const int rs = w * 14;                    // slice start row: 0,14,28,42
    const int npair = (w < 3) ? 7 : 4;        // row-pairs: W0-2 14 rows, W3 8

    for (int i = 0; i < 8; ++i) {
        const int b = blockIdx.x * 8 + i;
        const size_t rowbase = (size_t)b * 50;

        // ---- DMA stage: per-lane global src (+l*4 floats = l*16B), uniform LDS dest
        for (int j = 0; j < npair; ++j) {
            gl_lds16(a_emb + (rowbase + rs + 2 * j) * 128 + l * 4, &aL[w][j * 256]);
            gl_lds16(o_emb + (rowbase + rs + 2 * j) * 128 + l * 4, &oL[w][j * 256]);
        }
        if (w == 0) {
#pragma unroll
            for (int j = 0; j < 3; ++j)
                gl_lds16(v + (size_t)b * RD + j * 256 + l * 4, &vL[j * 256]);
        }
        if (tid < 50) sL[tid] = s[rowbase + tid];
        __syncthreads();   // drains vmcnt(0): all staged data visible

        // ---- compute from LDS: half h handles row rs + 2r + h
#pragma unroll 2
        for (int r = 0; r < npair; ++r) {
            const int lr = 2 * r + half;
            const int n  = rs + lr;
            const int rel = sL[n];
            const float4 xa = *(const float4*)(&aL[w][lr * 128 + ll * 4]);
            const float4 xo = *(const float4*)(&oL[w][lr * 128 + ll * 4]);
            const float4 va = *(const float4*)(&vL[rel * 256 + ll * 4]);
            const float4 vo = *(const float4*)(&vL[rel * 256 + 128 + ll * 4]);
            float ps = xa.x * va.x + xa.y * va.y + xa.z * va.z + xa.w * va.w
                     + xo.x * vo.x + xo.y * vo.y + xo.z * vo.z + xo.w * vo.w;
#pragma unroll
            for (int off = 16; off >= 1; off >>= 1) ps += __shfl_xor(ps, off, 64);
            if (ll == 0) out[rowbase + n] = ps;
        }
        __syncthreads();   // compute done before next b's DMA overwrites LDS
    }
}

extern "C" void kernel_launch(void* const* d_in, const int* in_sizes, int n_in,
                              void* d_out, int out_size, void* d_ws, size_t ws_size,
                              hipStream_t stream)
{
    const float* u_emb   = (const float*)d_in[0];
    const float* i_emb   = (const float*)d_in[1];
    const float* a_emb   = (const float*)d_in[2];
    const float* o_emb   = (const float*)d_in[3];
    const float* w_aor   = (const float*)d_in[4];
    const float* w_uir   = (const float*)d_in[5];
    const float* r_param = (const float*)d_in[6];
    const int*   s       = (const int*)d_in[7];
    float* out = (float*)d_out;

    float* v    = (float*)d_ws;                     // [4096][768]
    float* w2t  = v + (size_t)4096 * RD;            // [768][256]
    float* cvec = w2t + (size_t)RD * TWO_D;         // [768]

    relproj_kernel<<<dim3(4, 4, 3), 256, 0, stream>>>(w_aor, w_uir, r_param, w2t, cvec);
    vproj_kernel<<<dim3(4096 / 64, RD / 32), 256, 0, stream>>>(u_emb, i_emb, w2t, cvec, v);
    score_kernel<<<512, 256, 0, stream>>>(a_emb, o_emb, v, s, out);
}